// Round 1
// baseline (101.180 us; speedup 1.0000x reference)
//
#include <hip/hip_runtime.h>

// LaneNet discriminative loss, MI355X.
// preds: (4, 8, 280, 640) f32 ; targets: (4, 280, 640) i32 ; group_num = 5.
// out: [loss_dist, loss_var*0.01, loss_reg] f32.
//
// ws layout (floats):
//   S[4][5][8]  @ 0    : per-(n,g) channel sums           (160)
//   K[4][5]     @ 160  : per-(n,g) point counts           (20)
//   V[4]        @ 180  : per-n variance-loss partial sums (4)

#define P_TOTAL (280 * 640)   // 179200 = 175 * 256 * 4
#define NBATCH 4
#define GN 5
#define CC 8

#define WAVE_RED(x)                          \
  do {                                       \
    x += __shfl_xor(x, 32, 64);              \
    x += __shfl_xor(x, 16, 64);              \
    x += __shfl_xor(x, 8, 64);               \
    x += __shfl_xor(x, 4, 64);               \
    x += __shfl_xor(x, 2, 64);               \
    x += __shfl_xor(x, 1, 64);               \
  } while (0)

__global__ __launch_bounds__(256) void k_accum(const float* __restrict__ preds,
                                               const int* __restrict__ targets,
                                               float* __restrict__ ws) {
  const int n = blockIdx.y;
  const int tid = threadIdx.x;
  const int p4 = (blockIdx.x * 256 + tid) * 4;   // exact coverage: 175*256*4 = P_TOTAL

  const float* pn = preds + (size_t)n * CC * P_TOTAL;
  const int* tn = targets + (size_t)n * P_TOTAL;

  float acc[GN][CC];
  float cnt[GN];
#pragma unroll
  for (int g = 0; g < GN; ++g) {
    cnt[g] = 0.0f;
#pragma unroll
    for (int c = 0; c < CC; ++c) acc[g][c] = 0.0f;
  }

  if (p4 < P_TOTAL) {
    int4 t4 = *reinterpret_cast<const int4*>(tn + p4);
    int t[4] = {t4.x, t4.y, t4.z, t4.w};
    float4 v4[CC];
#pragma unroll
    for (int c = 0; c < CC; ++c)
      v4[c] = *reinterpret_cast<const float4*>(pn + (size_t)c * P_TOTAL + p4);
    float v[CC][4];
#pragma unroll
    for (int c = 0; c < CC; ++c) {
      v[c][0] = v4[c].x; v[c][1] = v4[c].y; v[c][2] = v4[c].z; v[c][3] = v4[c].w;
    }
#pragma unroll
    for (int s = 0; s < 4; ++s) {
#pragma unroll
      for (int g = 0; g < GN; ++g) {
        float m = (t[s] == g + 1) ? 1.0f : 0.0f;
        cnt[g] += m;
#pragma unroll
        for (int c = 0; c < CC; ++c) acc[g][c] = fmaf(m, v[c][s], acc[g][c]);
      }
    }
  }

  // wave-level reduction of 45 scalars
#pragma unroll
  for (int g = 0; g < GN; ++g) {
#pragma unroll
    for (int c = 0; c < CC; ++c) WAVE_RED(acc[g][c]);
    WAVE_RED(cnt[g]);
  }

  __shared__ float red[4][GN * CC + GN];   // 4 waves x 45
  const int lane = tid & 63;
  const int wv = tid >> 6;
  if (lane == 0) {
#pragma unroll
    for (int g = 0; g < GN; ++g) {
#pragma unroll
      for (int c = 0; c < CC; ++c) red[wv][g * CC + c] = acc[g][c];
      red[wv][GN * CC + g] = cnt[g];
    }
  }
  __syncthreads();
  if (tid < GN * CC + GN) {
    float s = red[0][tid] + red[1][tid] + red[2][tid] + red[3][tid];
    if (tid < GN * CC)
      atomicAdd(&ws[n * (GN * CC) + tid], s);
    else
      atomicAdd(&ws[NBATCH * GN * CC + n * GN + (tid - GN * CC)], s);
  }
}

__global__ __launch_bounds__(256) void k_var(const float* __restrict__ preds,
                                             const int* __restrict__ targets,
                                             float* __restrict__ ws) {
  const int n = blockIdx.y;
  const int tid = threadIdx.x;

  __shared__ float center[GN][CC];
  if (tid < GN * CC) {
    int g = tid >> 3;
    center[g][tid & 7] =
        ws[n * (GN * CC) + tid] / (ws[NBATCH * GN * CC + n * GN + g] + 1e-5f);
  }
  __syncthreads();

  const float* pn = preds + (size_t)n * CC * P_TOTAL;
  const int* tn = targets + (size_t)n * P_TOTAL;
  const int p4 = (blockIdx.x * 256 + tid) * 4;

  float accv = 0.0f;
  if (p4 < P_TOTAL) {
    int4 t4 = *reinterpret_cast<const int4*>(tn + p4);
    int t[4] = {t4.x, t4.y, t4.z, t4.w};
    float4 v4[CC];
#pragma unroll
    for (int c = 0; c < CC; ++c)
      v4[c] = *reinterpret_cast<const float4*>(pn + (size_t)c * P_TOTAL + p4);
    float v[CC][4];
#pragma unroll
    for (int c = 0; c < CC; ++c) {
      v[c][0] = v4[c].x; v[c][1] = v4[c].y; v[c][2] = v4[c].z; v[c][3] = v4[c].w;
    }
#pragma unroll
    for (int s = 0; s < 4; ++s) {
      int ts = t[s];
      if (ts > 0) {
        int g = ts - 1;
        float ss = 0.0f;
#pragma unroll
        for (int c = 0; c < CC; ++c) {
          float d = v[c][s] - center[g][c];
          ss = fmaf(d, d, ss);
        }
        float dn = sqrtf(ss);            // safe_norm: dn==0 when ss==0, clip kills it anyway
        float cl = fmaxf(dn - 0.2f, 0.0f);
        accv = fmaf(cl, cl, accv);
      }
    }
  }

  WAVE_RED(accv);
  __shared__ float red[4];
  const int lane = tid & 63;
  const int wv = tid >> 6;
  if (lane == 0) red[wv] = accv;
  __syncthreads();
  if (tid == 0) {
    float s = red[0] + red[1] + red[2] + red[3];
    atomicAdd(&ws[NBATCH * GN * CC + NBATCH * GN + n], s);
  }
}

__global__ __launch_bounds__(64) void k_final(const float* __restrict__ ws,
                                              float* __restrict__ out) {
  const int tid = threadIdx.x;
  __shared__ float sdist[NBATCH], svar[NBATCH], sreg[NBATCH];
  if (tid < NBATCH) {
    const int n = tid;
    float center[GN][CC];
    float has[GN];
    float ng = 0.0f;
#pragma unroll
    for (int g = 0; g < GN; ++g) {
      float c_ = ws[NBATCH * GN * CC + n * GN + g];
      has[g] = (c_ > 0.0f) ? 1.0f : 0.0f;
      ng += has[g];
#pragma unroll
      for (int c = 0; c < CC; ++c)
        center[g][c] = ws[n * (GN * CC) + g * CC + c] / (c_ + 1e-5f);
    }
    // variance term (already summed over points) / n_groups
    float lv = ws[NBATCH * GN * CC + NBATCH * GN + n] / ng;
    // pairwise center distance term; row i masked by has[i]; diagonal included
    float ld = 0.0f;
#pragma unroll
    for (int i = 0; i < GN; ++i) {
#pragma unroll
      for (int j = 0; j < GN; ++j) {
        float ss = 0.0f;
#pragma unroll
        for (int c = 0; c < CC; ++c) {
          float d = center[j][c] - center[i][c];
          ss = fmaf(d, d, ss);
        }
        float dn = (ss > 0.0f) ? sqrtf(ss) : 0.0f;  // safe_norm
        float cl = fmaxf(1.2f - dn, 0.0f);
        ld += cl * cl * has[i];
      }
    }
    ld /= fmaxf(ng * (ng - 1.0f), 1.0f);
    // regularization
    float lr = 0.0f;
#pragma unroll
    for (int g = 0; g < GN; ++g) {
      float cs = 0.0f;
#pragma unroll
      for (int c = 0; c < CC; ++c) cs += center[g][c];
      lr += cs * cs * has[g];
    }
    sdist[n] = ld;
    svar[n] = lv;
    sreg[n] = lr;
  }
  __syncthreads();
  if (tid == 0) {
    float d = 0.0f, v = 0.0f, r = 0.0f;
#pragma unroll
    for (int n = 0; n < NBATCH; ++n) { d += sdist[n]; v += svar[n]; r += sreg[n]; }
    out[0] = d * 0.25f;
    out[1] = v * 0.25f * 0.01f;
    out[2] = r * 0.001f;
  }
}

extern "C" void kernel_launch(void* const* d_in, const int* in_sizes, int n_in,
                              void* d_out, int out_size, void* d_ws, size_t ws_size,
                              hipStream_t stream) {
  const float* preds = (const float*)d_in[0];
  const int* targets = (const int*)d_in[1];
  float* out = (float*)d_out;
  float* ws = (float*)d_ws;

  // zero the 184-float accumulator region (ws is poisoned before every launch)
  hipMemsetAsync(ws, 0, (NBATCH * GN * CC + NBATCH * GN + NBATCH) * sizeof(float),
                 stream);

  dim3 grid(P_TOTAL / (256 * 4), NBATCH);   // (175, 4)
  k_accum<<<grid, 256, 0, stream>>>(preds, targets, ws);
  k_var<<<grid, 256, 0, stream>>>(preds, targets, ws);
  k_final<<<1, 64, 0, stream>>>(ws, out);
}

// Round 4
// 96.866 us; speedup vs baseline: 1.0445x; 1.0445x over previous
//
#include <hip/hip_runtime.h>

// LaneNet discriminative loss, MI355X.
// preds: (4, 8, 280, 640) f32 ; targets: (4, 280, 640) i32 ; group_num = 5.
// out: [loss_dist, loss_var*0.01, loss_reg] f32.
//
// ws layout (floats):
//   S[4][5][8]  @ 0    : per-(n,g) channel sums           (160)
//   K[4][5]     @ 160  : per-(n,g) point counts           (20)
//   V[4]        @ 180  : per-n variance-loss partial sums (4)

#define P_TOTAL (280 * 640)   // 179200 = 175 * 256 * 4
#define NBATCH 4
#define GN 5
#define CC 8
#define NVAL (GN * CC + GN)   // 45 block-reduced scalars
#define LPAD 47               // row stride (words); 47 odd => 2-way write aliasing (free)

#define WAVE_RED(x)                          \
  do {                                       \
    x += __shfl_xor(x, 32, 64);              \
    x += __shfl_xor(x, 16, 64);              \
    x += __shfl_xor(x, 8, 64);               \
    x += __shfl_xor(x, 4, 64);               \
    x += __shfl_xor(x, 2, 64);               \
    x += __shfl_xor(x, 1, 64);               \
  } while (0)

__global__ __launch_bounds__(256) void k_accum(const float* __restrict__ preds,
                                               const int* __restrict__ targets,
                                               float* __restrict__ ws) {
  const int n = blockIdx.y;
  const int tid = threadIdx.x;
  const int p4 = (blockIdx.x * 256 + tid) * 4;   // exact coverage: 175*256*4 = P_TOTAL

  const float* pn = preds + (size_t)n * CC * P_TOTAL;
  const int* tn = targets + (size_t)n * P_TOTAL;

  float acc[GN][CC];
  float cnt[GN];
#pragma unroll
  for (int g = 0; g < GN; ++g) {
    cnt[g] = 0.0f;
#pragma unroll
    for (int c = 0; c < CC; ++c) acc[g][c] = 0.0f;
  }

  {
    int4 t4 = *reinterpret_cast<const int4*>(tn + p4);
    int t[4] = {t4.x, t4.y, t4.z, t4.w};
    float4 v4[CC];
#pragma unroll
    for (int c = 0; c < CC; ++c)
      v4[c] = *reinterpret_cast<const float4*>(pn + (size_t)c * P_TOTAL + p4);
    float v[CC][4];
#pragma unroll
    for (int c = 0; c < CC; ++c) {
      v[c][0] = v4[c].x; v[c][1] = v4[c].y; v[c][2] = v4[c].z; v[c][3] = v4[c].w;
    }
#pragma unroll
    for (int s = 0; s < 4; ++s) {
#pragma unroll
      for (int g = 0; g < GN; ++g) {
        float m = (t[s] == g + 1) ? 1.0f : 0.0f;
        cnt[g] += m;
#pragma unroll
        for (int c = 0; c < CC; ++c) acc[g][c] = fmaf(m, v[c][s], acc[g][c]);
      }
    }
  }

  // ---- block reduction via LDS transpose (no per-thread butterfly) ----
  __shared__ float buf[256][LPAD];
  __shared__ float part4[NVAL][4];
#pragma unroll
  for (int g = 0; g < GN; ++g) {
#pragma unroll
    for (int c = 0; c < CC; ++c) buf[tid][g * CC + c] = acc[g][c];
    buf[tid][GN * CC + g] = cnt[g];
  }
  __syncthreads();

  if (tid < NVAL * 4) {
    const int k = tid >> 2;        // 0..44 : which scalar
    const int part = tid & 3;      // 0..3  : row subset (interleaved => distinct banks)
    float s = 0.0f;
#pragma unroll
    for (int r = 0; r < 64; ++r) s += buf[(r << 2) + part][k];
    part4[k][part] = s;
  }
  __syncthreads();

  if (tid < NVAL) {
    float s = part4[tid][0] + part4[tid][1] + part4[tid][2] + part4[tid][3];
    if (tid < GN * CC)
      atomicAdd(&ws[n * (GN * CC) + tid], s);
    else
      atomicAdd(&ws[NBATCH * GN * CC + n * GN + (tid - GN * CC)], s);
  }
}

__global__ __launch_bounds__(256) void k_var(const float* __restrict__ preds,
                                             const int* __restrict__ targets,
                                             float* __restrict__ ws) {
  const int n = blockIdx.y;
  const int tid = threadIdx.x;

  __shared__ float center[GN][CC];
  if (tid < GN * CC) {
    int g = tid >> 3;
    center[g][tid & 7] =
        ws[n * (GN * CC) + tid] / (ws[NBATCH * GN * CC + n * GN + g] + 1e-5f);
  }
  __syncthreads();

  const float* pn = preds + (size_t)n * CC * P_TOTAL;
  const int* tn = targets + (size_t)n * P_TOTAL;
  const int p4 = (blockIdx.x * 256 + tid) * 4;

  float accv = 0.0f;
  {
    int4 t4 = *reinterpret_cast<const int4*>(tn + p4);
    int t[4] = {t4.x, t4.y, t4.z, t4.w};
    float4 v4[CC];
#pragma unroll
    for (int c = 0; c < CC; ++c)
      v4[c] = *reinterpret_cast<const float4*>(pn + (size_t)c * P_TOTAL + p4);
    float v[CC][4];
#pragma unroll
    for (int c = 0; c < CC; ++c) {
      v[c][0] = v4[c].x; v[c][1] = v4[c].y; v[c][2] = v4[c].z; v[c][3] = v4[c].w;
    }
#pragma unroll
    for (int s = 0; s < 4; ++s) {
      int ts = t[s];
      if (ts > 0) {
        int g = ts - 1;
        float ss = 0.0f;
#pragma unroll
        for (int c = 0; c < CC; ++c) {
          float d = v[c][s] - center[g][c];
          ss = fmaf(d, d, ss);
        }
        float dn = sqrtf(ss);            // safe_norm: dn==0 when ss==0, clip kills it anyway
        float cl = fmaxf(dn - 0.2f, 0.0f);
        accv = fmaf(cl, cl, accv);
      }
    }
  }

  WAVE_RED(accv);
  __shared__ float red[4];
  const int lane = tid & 63;
  const int wv = tid >> 6;
  if (lane == 0) red[wv] = accv;
  __syncthreads();
  if (tid == 0) {
    float s = red[0] + red[1] + red[2] + red[3];
    atomicAdd(&ws[NBATCH * GN * CC + NBATCH * GN + n], s);
  }
}

__global__ __launch_bounds__(64) void k_final(const float* __restrict__ ws,
                                              float* __restrict__ out) {
  const int tid = threadIdx.x;
  __shared__ float sdist[NBATCH], svar[NBATCH], sreg[NBATCH];
  if (tid < NBATCH) {
    const int n = tid;
    float center[GN][CC];
    float has[GN];
    float ng = 0.0f;
#pragma unroll
    for (int g = 0; g < GN; ++g) {
      float c_ = ws[NBATCH * GN * CC + n * GN + g];
      has[g] = (c_ > 0.0f) ? 1.0f : 0.0f;
      ng += has[g];
#pragma unroll
      for (int c = 0; c < CC; ++c)
        center[g][c] = ws[n * (GN * CC) + g * CC + c] / (c_ + 1e-5f);
    }
    // variance term (already summed over points) / n_groups
    float lv = ws[NBATCH * GN * CC + NBATCH * GN + n] / ng;
    // pairwise center distance term; rows masked by has[i]; diagonal included
    float ld = 0.0f;
#pragma unroll
    for (int i = 0; i < GN; ++i) {
#pragma unroll
      for (int j = 0; j < GN; ++j) {
        float ss = 0.0f;
#pragma unroll
        for (int c = 0; c < CC; ++c) {
          float d = center[j][c] - center[i][c];
          ss = fmaf(d, d, ss);
        }
        float dn = (ss > 0.0f) ? sqrtf(ss) : 0.0f;  // safe_norm
        float cl = fmaxf(1.2f - dn, 0.0f);
        ld += cl * cl * has[i];
      }
    }
    ld /= fmaxf(ng * (ng - 1.0f), 1.0f);
    // regularization
    float lr = 0.0f;
#pragma unroll
    for (int g = 0; g < GN; ++g) {
      float cs = 0.0f;
#pragma unroll
      for (int c = 0; c < CC; ++c) cs += center[g][c];
      lr += cs * cs * has[g];
    }
    sdist[n] = ld;
    svar[n] = lv;
    sreg[n] = lr;
  }
  __syncthreads();
  if (tid == 0) {
    float d = 0.0f, v = 0.0f, r = 0.0f;
#pragma unroll
    for (int n = 0; n < NBATCH; ++n) { d += sdist[n]; v += svar[n]; r += sreg[n]; }
    out[0] = d * 0.25f;
    out[1] = v * 0.25f * 0.01f;
    out[2] = r * 0.001f;
  }
}

extern "C" void kernel_launch(void* const* d_in, const int* in_sizes, int n_in,
                              void* d_out, int out_size, void* d_ws, size_t ws_size,
                              hipStream_t stream) {
  const float* preds = (const float*)d_in[0];
  const int* targets = (const int*)d_in[1];
  float* out = (float*)d_out;
  float* ws = (float*)d_ws;

  // zero the 184-float accumulator region (ws is poisoned before every launch)
  hipMemsetAsync(ws, 0, (NBATCH * GN * CC + NBATCH * GN + NBATCH) * sizeof(float),
                 stream);

  dim3 grid(P_TOTAL / (256 * 4), NBATCH);   // (175, 4)
  k_accum<<<grid, 256, 0, stream>>>(preds, targets, ws);
  k_var<<<grid, 256, 0, stream>>>(preds, targets, ws);
  k_final<<<1, 64, 0, stream>>>(ws, out);
}